// Round 1
// baseline (492.870 us; speedup 1.0000x reference)
//
#include <hip/hip_runtime.h>
#include <hip/hip_bf16.h>

#define N_    2
#define T_    7
#define C_    96
#define H_    96
#define W_    96
#define HW_   9216
#define HEAD_ 4
#define HD_   24
#define C3_   288
#define P_    32           // pixels per block
#define QP_   97           // padded stride for q/k tiles
#define CATP_ 292          // padded stride for cat tile (mult of 4 for float4)
#define NBLK_ (N_ * (HW_ / P_))   // 576

typedef unsigned int u32;

__device__ __forceinline__ float bits2f(u32 b) {
    union { u32 u; float f; } x; x.u = b; return x.f;
}

template<bool BF16>
__device__ __forceinline__ float ld1(const void* p, int i) {
    if constexpr (BF16) return bits2f(((u32)((const unsigned short*)p)[i]) << 16);
    else                return ((const float*)p)[i];
}

// load 4 consecutive elements starting at i (i % 4 == 0)
template<bool BF16>
__device__ __forceinline__ void ld4w(const void* p, int i, float w[4]) {
    if constexpr (BF16) {
        const uint2 u = ((const uint2*)p)[i >> 2];
        w[0] = bits2f(u.x << 16);
        w[1] = bits2f(u.x & 0xFFFF0000u);
        w[2] = bits2f(u.y << 16);
        w[3] = bits2f(u.y & 0xFFFF0000u);
    } else {
        const float4 v = *((const float4*)((const float*)p + i));
        w[0] = v.x; w[1] = v.y; w[2] = v.z; w[3] = v.w;
    }
}

template<bool BF16>
__device__ __forceinline__ void st1(void* p, int i, float v) {
    if constexpr (BF16) ((__hip_bfloat16*)p)[i] = __float2bfloat16(v);
    else                ((float*)p)[i] = v;
}

// ---- dtype detector: bf16 bit patterns of N(0,1) data cluster in the
// exponent window; f32 low-16 bits are ~uniform. Writes 1 (bf16) / 0 (f32).
__global__ void detect_dtype_kernel(const u32* __restrict__ w, int* __restrict__ flag) {
    u32 x = w[threadIdx.x];
    u32 f = x & 0x7FFFu;                       // low bf16 element's magnitude bits
    int inwin = (f >= 0x3A00u) && (f <= 0x4200u);
    unsigned long long m = __ballot(inwin);
    if (threadIdx.x == 0) flag[0] = (__popcll(m) >= 40) ? 1 : 0;
}

template<bool BF16>
__global__ __launch_bounds__(256) void traj_main(
    const void* __restrict__ curr, const void* __restrict__ idxf,
    const void* __restrict__ anchor, const void* __restrict__ s1,
    const void* __restrict__ s2, const void* __restrict__ s3,
    const void* __restrict__ loc, const void* __restrict__ pw,
    const void* __restrict__ pb, const void* __restrict__ fw,
    const void* __restrict__ fb, void* __restrict__ outp,
    const int* __restrict__ flag)
{
    if ((*flag != 0) != BF16) return;   // uniform early-exit for the wrong-dtype instantiation

    __shared__ __align__(16) float s_u[P_ * CATP_];      // cat tile; overlays q [0,3104) and k [3104,6208)
    __shared__ __align__(16) float s_mid[P_][100];       // fusion output, padded
    __shared__ int   s_lin[T_][P_];
    __shared__ float s_red[P_][8];
    __shared__ float s_best[P_][HEAD_];
    __shared__ int   s_bidx[P_][HEAD_];
    __shared__ float s_inv[P_];

#define S_Q(pp, ch)  s_u[(pp) * QP_ + (ch)]
#define S_K(pp, ch)  s_u[3104 + (pp) * QP_ + (ch)]
#define S_CAT(pp, d) s_u[(pp) * CATP_ + (d)]

    const int tid = threadIdx.x;
    const int b  = blockIdx.x;
    const int nn = b / (HW_ / P_);
    const int p0 = (b - nn * (HW_ / P_)) * P_;

    // ---- nearest-sample indices (mirror reference f32 op sequence exactly) ----
    if (tid < T_ * P_) {
        int t = tid / P_, pp = tid - t * P_;
        int p = p0 + pp;
        float x = ld1<BF16>(loc, (nn * 2 * T_ + 2 * t    ) * HW_ + p);
        float y = ld1<BF16>(loc, (nn * 2 * T_ + 2 * t + 1) * HW_ + p);
        float gx = 2.0f * x / 95.0f - 1.0f;
        float gy = 2.0f * y / 95.0f - 1.0f;
        float fx = (gx + 1.0f) * 0.5f * 95.0f;
        float fy = (gy + 1.0f) * 0.5f * 95.0f;
        float ix = rintf(fx), iy = rintf(fy);     // round-half-even == jnp.round
        bool v = (ix >= 0.0f) && (ix <= 95.0f) && (iy >= 0.0f) && (iy <= 95.0f);
        s_lin[t][pp] = v ? ((int)iy * W_ + (int)ix) : -1;
    }
    if (tid < P_ * HEAD_) { s_best[tid >> 2][tid & 3] = -3.0e38f; s_bidx[tid >> 2][tid & 3] = 0; }

    // ---- load curr (coalesced along pixels) ----
    for (int i = tid; i < C_ * P_; i += 256) {
        int ch = i / P_, pp = i - ch * P_;
        S_Q(pp, ch) = ld1<BF16>(curr, (nn * C_ + ch) * HW_ + p0 + pp);
    }
    __syncthreads();
    // ---- q L2 norm over full c (before head split) ----
    {
        int pp = tid >> 3, j = tid & 7;
        float s = 0.f;
        #pragma unroll
        for (int k = 0; k < 12; ++k) { float v = S_Q(pp, j * 12 + k); s += v * v; }
        s_red[pp][j] = s;
    }
    __syncthreads();
    if (tid < P_) {
        float s = 0.f;
        #pragma unroll
        for (int j = 0; j < 8; ++j) s += s_red[tid][j];
        s_inv[tid] = 1.0f / fmaxf(sqrtf(s), 1e-12f);
    }
    __syncthreads();
    for (int i = tid; i < C_ * P_; i += 256) {
        int ch = i / P_, pp = i - ch * P_;
        S_Q(pp, ch) *= s_inv[pp];
    }

    // ---- per-frame: gather k, normalize, multi-head scores, running argmax ----
    for (int t = 0; t < T_; ++t) {
        __syncthreads();
        for (int i = tid; i < C_ * P_; i += 256) {
            int ch = i / P_, pp = i - ch * P_;
            int lin = s_lin[t][pp];
            S_K(pp, ch) = (lin >= 0) ? ld1<BF16>(idxf, ((nn * T_ + t) * C_ + ch) * HW_ + lin) : 0.0f;
        }
        __syncthreads();
        {
            int pp = tid >> 3, j = tid & 7;
            float s = 0.f;
            #pragma unroll
            for (int k = 0; k < 12; ++k) { float v = S_K(pp, j * 12 + k); s += v * v; }
            s_red[pp][j] = s;
        }
        __syncthreads();
        if (tid < P_) {
            float s = 0.f;
            #pragma unroll
            for (int j = 0; j < 8; ++j) s += s_red[tid][j];
            s_inv[tid] = 1.0f / fmaxf(sqrtf(s), 1e-12f);
        }
        __syncthreads();
        if (tid < P_ * HEAD_) {
            int pp = tid >> 2, h = tid & 3;
            float s = 0.f;
            #pragma unroll
            for (int d = 0; d < HD_; ++d) s += S_K(pp, h * HD_ + d) * S_Q(pp, h * HD_ + d);
            s *= s_inv[pp];
            if (s > s_best[pp][h]) { s_best[pp][h] = s; s_bidx[pp][h] = t; }  // strict > == first-max
        }
    }
    __syncthreads();

    // ---- gather winning frames from s1/s2/s3 into cat (overlays q/k region) ----
    for (int i = tid; i < C3_ * P_; i += 256) {
        int pp = i / C3_, d = i - pp * C3_;
        int set = d / C_, ch = d - set * C_;
        int h = ch / HD_;
        int bt = s_bidx[pp][h];
        int lin = s_lin[bt][pp];
        float v = 0.f;
        if (lin >= 0) {
            const void* sp = (set == 0) ? s1 : (set == 1) ? s2 : s3;
            v = ld1<BF16>(sp, ((nn * T_ + bt) * C_ + ch) * HW_ + lin);
        }
        S_CAT(pp, d) = v;
    }
    __syncthreads();

    // ---- fusion GEMV (96 x 288) + bias, scaled by per-head max score ----
    for (int u = tid; u < 24 * P_; u += 256) {
        int cog = u / P_, pp = u - cog * P_;
        int co0 = cog * 4;                       // 4 co's never straddle a head (24 % 4 == 0)
        float a0 = 0.f, a1 = 0.f, a2 = 0.f, a3 = 0.f;
        for (int d = 0; d < C3_; d += 4) {
            const float4 cv = *((const float4*)&S_CAT(pp, d));
            float w[4];
            ld4w<BF16>(fw, (co0 + 0) * C3_ + d, w);
            a0 += w[0] * cv.x + w[1] * cv.y + w[2] * cv.z + w[3] * cv.w;
            ld4w<BF16>(fw, (co0 + 1) * C3_ + d, w);
            a1 += w[0] * cv.x + w[1] * cv.y + w[2] * cv.z + w[3] * cv.w;
            ld4w<BF16>(fw, (co0 + 2) * C3_ + d, w);
            a2 += w[0] * cv.x + w[1] * cv.y + w[2] * cv.z + w[3] * cv.w;
            ld4w<BF16>(fw, (co0 + 3) * C3_ + d, w);
            a3 += w[0] * cv.x + w[1] * cv.y + w[2] * cv.z + w[3] * cv.w;
        }
        float soft = s_best[pp][co0 / HD_];
        s_mid[pp][co0 + 0] = (a0 + ld1<BF16>(fb, co0 + 0)) * soft;
        s_mid[pp][co0 + 1] = (a1 + ld1<BF16>(fb, co0 + 1)) * soft;
        s_mid[pp][co0 + 2] = (a2 + ld1<BF16>(fb, co0 + 2)) * soft;
        s_mid[pp][co0 + 3] = (a3 + ld1<BF16>(fb, co0 + 3)) * soft;
    }
    __syncthreads();

    // ---- proj GEMV (96 x 96) + bias + anchor, store ----
    for (int u = tid; u < 24 * P_; u += 256) {
        int dog = u / P_, pp = u - dog * P_;
        int do0 = dog * 4;
        float a0 = 0.f, a1 = 0.f, a2 = 0.f, a3 = 0.f;
        for (int c = 0; c < C_; c += 4) {
            const float4 mv = *((const float4*)&s_mid[pp][c]);
            float w[4];
            ld4w<BF16>(pw, (do0 + 0) * C_ + c, w);
            a0 += w[0] * mv.x + w[1] * mv.y + w[2] * mv.z + w[3] * mv.w;
            ld4w<BF16>(pw, (do0 + 1) * C_ + c, w);
            a1 += w[0] * mv.x + w[1] * mv.y + w[2] * mv.z + w[3] * mv.w;
            ld4w<BF16>(pw, (do0 + 2) * C_ + c, w);
            a2 += w[0] * mv.x + w[1] * mv.y + w[2] * mv.z + w[3] * mv.w;
            ld4w<BF16>(pw, (do0 + 3) * C_ + c, w);
            a3 += w[0] * mv.x + w[1] * mv.y + w[2] * mv.z + w[3] * mv.w;
        }
        int p = p0 + pp;
        float r0 = a0 + ld1<BF16>(pb, do0 + 0) + ld1<BF16>(anchor, (nn * C_ + do0 + 0) * HW_ + p);
        float r1 = a1 + ld1<BF16>(pb, do0 + 1) + ld1<BF16>(anchor, (nn * C_ + do0 + 1) * HW_ + p);
        float r2 = a2 + ld1<BF16>(pb, do0 + 2) + ld1<BF16>(anchor, (nn * C_ + do0 + 2) * HW_ + p);
        float r3 = a3 + ld1<BF16>(pb, do0 + 3) + ld1<BF16>(anchor, (nn * C_ + do0 + 3) * HW_ + p);
        st1<BF16>(outp, (nn * C_ + do0 + 0) * HW_ + p, r0);
        st1<BF16>(outp, (nn * C_ + do0 + 1) * HW_ + p, r1);
        st1<BF16>(outp, (nn * C_ + do0 + 2) * HW_ + p, r2);
        st1<BF16>(outp, (nn * C_ + do0 + 3) * HW_ + p, r3);
    }
#undef S_Q
#undef S_K
#undef S_CAT
}

extern "C" void kernel_launch(void* const* d_in, const int* in_sizes, int n_in,
                              void* d_out, int out_size, void* d_ws, size_t ws_size,
                              hipStream_t stream) {
    (void)in_sizes; (void)n_in; (void)out_size; (void)ws_size;
    int* flag = (int*)d_ws;
    detect_dtype_kernel<<<1, 64, 0, stream>>>((const u32*)d_in[0], flag);
    dim3 grid(NBLK_), block(256);
    traj_main<true><<<grid, block, 0, stream>>>(d_in[0], d_in[1], d_in[2], d_in[3], d_in[4],
                                                d_in[5], d_in[6], d_in[7], d_in[8], d_in[9],
                                                d_in[10], d_out, flag);
    traj_main<false><<<grid, block, 0, stream>>>(d_in[0], d_in[1], d_in[2], d_in[3], d_in[4],
                                                 d_in[5], d_in[6], d_in[7], d_in[8], d_in[9],
                                                 d_in[10], d_out, flag);
}